// Round 14
// baseline (956.743 us; speedup 1.0000x reference)
//
#include <hip/hip_runtime.h>

#define B 128
#define C 32
#define HH 16
#define V 4096
#define TB 64
#define CB 256
#define MARGIN 2e-4f

// ---------------- helpers ----------------

__device__ __forceinline__ float cubicw(float t) {
    float at = fabsf(t);
    float at2 = at * at, at3 = at2 * at;
    if (at <= 1.f) return 1.25f * at3 - 2.25f * at2 + 1.f;
    if (at < 2.f)  return -0.75f * at3 + 3.75f * at2 - 6.f * at + 3.f;
    return 0.f;
}

// ---------------- kernels ----------------

// fused setup: f_rest=feat, f_hat=0, c2 (fp64+fp32), stage-0 z (global mean)
__global__ void setup_kernel(const float* __restrict__ feat, float* __restrict__ f_rest,
                             float* __restrict__ f_hat, const float* __restrict__ cb,
                             double* __restrict__ c2d, float* __restrict__ c2f,
                             float* __restrict__ z0) {
    int i = blockIdx.x * 256 + threadIdx.x;
    if (i < B * C * HH * HH) { f_rest[i] = feat[i]; f_hat[i] = 0.f; }
    if (i < V) {
        const float* p = cb + i * C;
        double s = 0.0;
        #pragma unroll
        for (int j = 0; j < C; ++j) { double d = (double)p[j]; s = fma(d, d, s); }
        c2d[i] = s;
        c2f[i] = (float)s;
    }
    if (i < B * C) {
        const float* p = feat + i * (HH * HH);
        float s = 0.f;
        for (int px = 0; px < HH * HH; ++px) s += p[px];
        z0[i] = s * (1.f / 256.f);
    }
}

// ---- GEMM-tiled fp32 top-2 scan (unchanged from R13: 40 KB LDS, 4 blocks/CU) ----
__global__ __launch_bounds__(256, 4) void scan_gemm_kernel(
    const float* __restrict__ z, const float* __restrict__ cb,
    const float* __restrict__ c2f, float* __restrict__ pb1,
    float* __restrict__ pb2, int* __restrict__ pi1,
    int npx, int nseg, int nblk_tok)
{
    int tid = threadIdx.x;
    int tb  = blockIdx.x % nblk_tok;
    int seg = blockIdx.x / nblk_tok;
    int cps = V / nseg;
    int sb  = seg * cps;
    int t0  = tb * TB;
    int total = B * npx;

    __shared__ float ldsZ[C][TB];
    __shared__ alignas(16) float ldsC[C][CB];
    float* mb1 = &ldsC[0][0];
    float* mb2 = mb1 + 32 * 68;
    int*   mi1 = (int*)(mb2 + 32 * 68);

    #pragma unroll
    for (int i = 0; i < 8; ++i) {
        int e = tid + i * 256;
        int c = e >> 6, t = e & 63;
        int tok = t0 + t;
        int bq = tok / npx, n = tok - bq * npx;
        ldsZ[c][t] = z[(bq * C + c) * npx + n];
    }

    int cg = tid & 31, tg = tid >> 5;

    float b1[8], b2[8]; int i1[8];
    #pragma unroll
    for (int i = 0; i < 8; ++i) { b1[i] = 3e38f; b2[i] = 3e38f; i1[i] = 0; }

    for (int tile = 0; tile < cps / CB; ++tile) {
        int code0 = sb + tile * CB;
        __syncthreads();
        {
            int cc = tid;
            const float4* cp = reinterpret_cast<const float4*>(cb + (size_t)(code0 + cc) * C);
            #pragma unroll
            for (int qq = 0; qq < 8; ++qq) {
                float4 q = cp[qq];
                ldsC[4 * qq + 0][cc] = q.x; ldsC[4 * qq + 1][cc] = q.y;
                ldsC[4 * qq + 2][cc] = q.z; ldsC[4 * qq + 3][cc] = q.w;
            }
        }
        float2 r01 = *reinterpret_cast<const float2*>(&c2f[code0 + 2 * cg]);
        float2 r23 = *reinterpret_cast<const float2*>(&c2f[code0 + 2 * cg + 64]);
        float2 r45 = *reinterpret_cast<const float2*>(&c2f[code0 + 2 * cg + 128]);
        float2 r67 = *reinterpret_cast<const float2*>(&c2f[code0 + 2 * cg + 192]);
        __syncthreads();

        float acc[8][8];
        #pragma unroll
        for (int i = 0; i < 8; ++i)
            #pragma unroll
            for (int j = 0; j < 8; ++j) acc[i][j] = 0.f;

        #pragma unroll 1
        for (int k = 0; k < C; ++k) {
            float4 z0v = *reinterpret_cast<const float4*>(&ldsZ[k][tg * 8]);
            float4 z1v = *reinterpret_cast<const float4*>(&ldsZ[k][tg * 8 + 4]);
            float2 c0 = *reinterpret_cast<const float2*>(&ldsC[k][2 * cg]);
            float2 c1 = *reinterpret_cast<const float2*>(&ldsC[k][2 * cg + 64]);
            float2 c2v = *reinterpret_cast<const float2*>(&ldsC[k][2 * cg + 128]);
            float2 c3 = *reinterpret_cast<const float2*>(&ldsC[k][2 * cg + 192]);
#define FMAROW(ti, zc) \
            acc[ti][0] = fmaf(zc, c0.x, acc[ti][0]); acc[ti][1] = fmaf(zc, c0.y, acc[ti][1]); \
            acc[ti][2] = fmaf(zc, c1.x, acc[ti][2]); acc[ti][3] = fmaf(zc, c1.y, acc[ti][3]); \
            acc[ti][4] = fmaf(zc, c2v.x, acc[ti][4]); acc[ti][5] = fmaf(zc, c2v.y, acc[ti][5]); \
            acc[ti][6] = fmaf(zc, c3.x, acc[ti][6]); acc[ti][7] = fmaf(zc, c3.y, acc[ti][7]);
            FMAROW(0, z0v.x) FMAROW(1, z0v.y) FMAROW(2, z0v.z) FMAROW(3, z0v.w)
            FMAROW(4, z1v.x) FMAROW(5, z1v.y) FMAROW(6, z1v.z) FMAROW(7, z1v.w)
#undef FMAROW
        }

        float rc2[8] = {r01.x, r01.y, r23.x, r23.y, r45.x, r45.y, r67.x, r67.y};
        #pragma unroll
        for (int j = 0; j < 8; ++j) {
            int code = code0 + 2 * cg + (j >> 1) * 64 + (j & 1);
            float cc2 = rc2[j];
            #pragma unroll
            for (int i = 0; i < 8; ++i) {
                float s = fmaf(-2.f, acc[i][j], cc2);
                if (s < b1[i]) { b2[i] = b1[i]; b1[i] = s; i1[i] = code; }
                else if (s < b2[i]) { b2[i] = s; }
            }
        }
    }

    __syncthreads();
    #pragma unroll
    for (int i = 0; i < 8; ++i) {
        mb1[cg * 68 + tg * 8 + i] = b1[i];
        mb2[cg * 68 + tg * 8 + i] = b2[i];
        mi1[cg * 68 + tg * 8 + i] = i1[i];
    }
    __syncthreads();
    if (tid < TB) {
        float gb1 = 3e38f, gb2 = 3e38f; int gi1 = 0;
        #pragma unroll
        for (int g = 0; g < 32; ++g) {
            float v1 = mb1[g * 68 + tid]; int ix = mi1[g * 68 + tid];
            if (v1 < gb1 || (v1 == gb1 && ix < gi1)) { gb2 = gb1; gb1 = v1; gi1 = ix; }
            else if (v1 < gb2) { gb2 = v1; }
            float v2 = mb2[g * 68 + tid];
            if (v2 < gb2) gb2 = v2;
        }
        int tok = t0 + tid;
        pb1[(size_t)seg * total + tok] = gb1;
        pb2[(size_t)seg * total + tok] = gb2;
        pi1[(size_t)seg * total + tok] = gi1;
    }
}

// combine per-seg top-2 ONCE per token; ambiguous -> exact fp64 rescan (block-parallel)
__global__ __launch_bounds__(256) void resolve_kernel(
    const float* __restrict__ pb1, const float* __restrict__ pb2,
    const int* __restrict__ pi1, const float* __restrict__ z,
    const float* __restrict__ cb, const double* __restrict__ c2d,
    int* __restrict__ idxf, int npx, int nseg)
{
    int total = B * npx;
    int tid = threadIdx.x;
    int tok = blockIdx.x * 256 + tid;

    __shared__ int flist[256];
    __shared__ int fcnt;
    if (tid == 0) fcnt = 0;
    __syncthreads();

    if (tok < total) {
        float gb1 = 3e38f, gb2 = 3e38f; int gi1 = 0;
        for (int s = 0; s < nseg; ++s) {
            float v1 = pb1[(size_t)s * total + tok];
            if (v1 < gb1) { gb2 = gb1; gb1 = v1; gi1 = pi1[(size_t)s * total + tok]; }
            else if (v1 < gb2) { gb2 = v1; }
            float v2 = pb2[(size_t)s * total + tok];
            if (v2 < gb2) gb2 = v2;
        }
        if (gb2 - gb1 >= MARGIN) {
            idxf[tok] = gi1;
        } else {
            int slot = atomicAdd(&fcnt, 1);
            flist[slot] = tok;
        }
    }
    __syncthreads();
    int nf = fcnt;
    if (nf == 0) return;

    __shared__ double zsd[C];
    __shared__ double sred[256];
    __shared__ int sidx[256];

    for (int f = 0; f < nf; ++f) {
        int t2 = flist[f];
        int bb = t2 / npx, n = t2 - bb * npx;
        if (tid < C) zsd[tid] = (double)z[(bb * C + tid) * npx + n];
        __syncthreads();
        double best = 1e300; int bi = 0x7fffffff;
        for (int k = 0; k < V / 256; ++k) {
            int v = tid + k * 256;
            const float4* cp = reinterpret_cast<const float4*>(cb + (size_t)v * C);
            double acc = 0.0;
            #pragma unroll
            for (int qq = 0; qq < 8; ++qq) {
                float4 fv = cp[qq];
                acc = fma((double)fv.x, zsd[4 * qq + 0], acc);
                acc = fma((double)fv.y, zsd[4 * qq + 1], acc);
                acc = fma((double)fv.z, zsd[4 * qq + 2], acc);
                acc = fma((double)fv.w, zsd[4 * qq + 3], acc);
            }
            double s = fma(-2.0, acc, c2d[v]);
            if (s < best || (s == best && v < bi)) { best = s; bi = v; }
        }
        sred[tid] = best; sidx[tid] = bi;
        __syncthreads();
        for (int st = 128; st > 0; st >>= 1) {
            if (tid < st) {
                double o = sred[tid + st]; int oi = sidx[tid + st];
                double me = sred[tid];     int mi = sidx[tid];
                if (o < me || (o == me && oi < mi)) { sred[tid] = o; sidx[tid] = oi; }
            }
            __syncthreads();
        }
        if (tid == 0) idxf[t2] = sidx[0];
        __syncthreads();
    }
}

// embed: gather 8 channels + separable bicubic (v-pass then h-pass) -> hu global
__global__ __launch_bounds__(256) void embed_kernel(
    const int* __restrict__ idxf, const float* __restrict__ cb,
    float* __restrict__ hu, int pn)
{
    int bb = blockIdx.x >> 2;
    int cg0 = (blockIdx.x & 3) * 8;
    int tid = threadIdx.x;
    int npx = pn * pn;

    __shared__ float h_s[8][257];
    __shared__ float t_s[8][257];
    __shared__ float wtab[16][4];
    __shared__ int   itab[16][4];

    if (tid < 16) {
        float scale = (float)pn * (1.f / 16.f);
        float src = (tid + 0.5f) * scale - 0.5f;
        int fi = (int)floorf(src);
        float t = src - (float)fi;
        #pragma unroll
        for (int k = 0; k < 4; ++k) {
            wtab[tid][k] = cubicw((float)(k - 1) - t);
            itab[tid][k] = min(max(fi + k - 1, 0), pn - 1);
        }
    }
    for (int e = tid; e < 8 * npx; e += 256) {
        int c = e & 7, n = e >> 3;
        h_s[c][n] = cb[idxf[bb * npx + n] * 32 + cg0 + c];
    }
    __syncthreads();

    // v-pass: t_s[c][p*pn + w] = sum_k wtab[p][k] * h_s[c][itab[p][k]*pn + w]
    for (int e = tid; e < 8 * 16 * pn; e += 256) {
        int w = e % pn; int rest = e / pn;
        int p = rest & 15, c = rest >> 4;
        float s = 0.f;
        #pragma unroll
        for (int k = 0; k < 4; ++k)
            s = fmaf(wtab[p][k], h_s[c][itab[p][k] * pn + w], s);
        t_s[c][p * pn + w] = s;
    }
    __syncthreads();

    // h-pass: hu[.][p*16+q] = sum_k wtab[q][k] * t_s[c][p*pn + itab[q][k]]
    #pragma unroll
    for (int it = 0; it < 8; ++it) {
        int e = tid + it * 256;
        int q = e & 15, p = (e >> 4) & 15, c = e >> 8;
        float s = 0.f;
        #pragma unroll
        for (int k = 0; k < 4; ++k)
            s = fmaf(wtab[q][k], t_s[c][p * pn + itab[q][k]], s);
        hu[(bb * 32 + cg0 + c) * 256 + (e & 255)] = s;
    }
}

// conv_tail: stage hu -> conv 8 out-ch -> blend/update f_hat,f_rest -> pools
__global__ __launch_bounds__(256) void conv_tail_kernel(
    const float* __restrict__ hu, const float* __restrict__ w,
    const float* __restrict__ bias, float* __restrict__ f_hat,
    float* __restrict__ f_rest, float* __restrict__ out,
    float* __restrict__ znext, int pn, int off, int pn2)
{
    int bb = blockIdx.x >> 2;
    int og = (blockIdx.x & 3) * 8;
    int tid = threadIdx.x;
    int npx = pn * pn;

    __shared__ float hu_s[32][260];      // 260: rows 16B-aligned, conflict-free
    float (*fh_s)[260] = &hu_s[0];       // overlay after conv reads complete
    float (*fr_s)[260] = &hu_s[8];

    float pf[8], pr[8];
    #pragma unroll
    for (int o = 0; o < 8; ++o) {
        int gi = (bb * 32 + og + o) * 256 + tid;
        pf[o] = f_hat[gi]; pr[o] = f_rest[gi];
    }

    const float4* hp4 = reinterpret_cast<const float4*>(hu + (size_t)bb * 32 * 256);
    #pragma unroll
    for (int it = 0; it < 8; ++it) {
        int e4 = tid + it * 256;
        int i = e4 >> 6, px = (e4 & 63) * 4;
        *reinterpret_cast<float4*>(&hu_s[i][px]) = hp4[e4];
    }
    __syncthreads();

    int p = tid >> 4, q = tid & 15;
    float acc[8];
    #pragma unroll
    for (int o = 0; o < 8; ++o) acc[o] = bias[og + o];
    for (int i = 0; i < 32; ++i) {
        float v[9];
        #pragma unroll
        for (int dy = 0; dy < 3; ++dy)
            #pragma unroll
            for (int dx = 0; dx < 3; ++dx) {
                int pp = p + dy - 1, qq = q + dx - 1;
                bool in = (pp >= 0) & (pp < 16) & (qq >= 0) & (qq < 16);
                v[dy * 3 + dx] = in ? hu_s[i][pp * 16 + qq] : 0.f;
            }
        #pragma unroll
        for (int o = 0; o < 8; ++o) {
            const float* wp_ = w + ((og + o) * 32 + i) * 9;
            #pragma unroll
            for (int k = 0; k < 9; ++k) acc[o] = fmaf(wp_[k], v[k], acc[o]);
        }
    }
    float hv[8];
    #pragma unroll
    for (int o = 0; o < 8; ++o) hv[o] = hu_s[og + o][tid];
    __syncthreads();   // all hu_s reads done before overlay writes

    #pragma unroll
    for (int o = 0; o < 8; ++o) {
        int gi = (bb * 32 + og + o) * 256 + tid;
        float blend = 0.5f * hv[o] + 0.5f * acc[o];
        float nf = pf[o] + blend;
        float nr = pr[o] - blend;
        f_hat[gi] = nf; f_rest[gi] = nr;
        fh_s[o][tid] = nf; fr_s[o][tid] = nr;
    }
    __syncthreads();

    for (int e = tid; e < 8 * npx; e += 256) {
        int o = e & 7, n = e >> 3;
        int y = n / pn, x = n - y * pn;
        int sh = (y * HH) / pn, eh = ((y + 1) * HH + pn - 1) / pn;
        int sw = (x * HH) / pn, ew = ((x + 1) * HH + pn - 1) / pn;
        float s = 0.f;
        for (int yy = sh; yy < eh; ++yy)
            for (int xx = sw; xx < ew; ++xx) s += fh_s[o][yy * 16 + xx];
        out[((bb * 680) + off + n) * 32 + og + o] = s * (1.f / (float)((eh - sh) * (ew - sw)));
    }

    if (pn2 > 0) {
        int npx2 = pn2 * pn2;
        for (int e = tid; e < 8 * npx2; e += 256) {
            int o = e / npx2, n = e - o * npx2;
            int y = n / pn2, x = n - y * pn2;
            int sh = (y * HH) / pn2, eh = ((y + 1) * HH + pn2 - 1) / pn2;
            int sw = (x * HH) / pn2, ew = ((x + 1) * HH + pn2 - 1) / pn2;
            float s = 0.f;
            for (int yy = sh; yy < eh; ++yy)
                for (int xx = sw; xx < ew; ++xx) s += fr_s[o][yy * 16 + xx];
            znext[(bb * 32 + og + o) * npx2 + n] = s * (1.f / (float)((eh - sh) * (ew - sw)));
        }
    }
}

// ---------------- launch ----------------

extern "C" void kernel_launch(void* const* d_in, const int* in_sizes, int n_in,
                              void* d_out, int out_size, void* d_ws, size_t ws_size,
                              hipStream_t stream) {
    const float* feat = (const float*)d_in[0];
    const float* cb   = (const float*)d_in[1];
    const float* phiw = (const float*)d_in[2];
    const float* phib = (const float*)d_in[3];
    float* out = (float*)d_out;
    float* wsf = (float*)d_ws;

    const int NE = B * C * HH * HH; // 1048576
    float* f_rest = wsf;
    float* f_hat  = wsf + NE;
    float* zA     = wsf + 2 * NE;
    float* zB     = wsf + 3 * NE;
    float* hu     = wsf + 4 * NE;
    char*  tl     = (char*)(wsf + 5 * NE);
    double* c2d  = (double*)tl;                       // 32 KB
    float*  c2f  = (float*)(tl + (32 << 10));         // 16 KB
    float*  pb1  = (float*)(tl + (48 << 10));                 // 1 MB (max 512 KB used)
    float*  pb2  = (float*)(tl + (48 << 10) + (1 << 20));
    int*    pi1  = (int*)  (tl + (48 << 10) + (2 << 20));
    int*    idxf = (int*)  (tl + (48 << 10) + (3 << 20));     // 128 KB

    static const int PN_[10]   = {1, 2, 3, 4, 5, 6, 8, 10, 13, 16};
    static const int PI_[10]   = {0, 0, 1, 1, 1, 2, 2, 2, 3, 3};
    static const int OFF_[10]  = {0, 1, 5, 14, 30, 55, 91, 155, 255, 424};
    static const int NSEG_[10] = {16, 16, 16, 16, 16, 16, 8, 8, 4, 4};

    setup_kernel<<<dim3((NE + 255) / 256), dim3(256), 0, stream>>>(
        feat, f_rest, f_hat, cb, c2d, c2f, zA);

    for (int si = 0; si < 10; ++si) {
        int pn = PN_[si], npx = pn * pn;
        int tokens = B * npx;
        int nseg = NSEG_[si];
        int nblk_tok = tokens / TB;
        float* zin  = (si & 1) ? zB : zA;
        float* zout = (si & 1) ? zA : zB;

        scan_gemm_kernel<<<dim3(nblk_tok * nseg), dim3(256), 0, stream>>>(
            zin, cb, c2f, pb1, pb2, pi1, npx, nseg, nblk_tok);

        resolve_kernel<<<dim3((tokens + 255) / 256), dim3(256), 0, stream>>>(
            pb1, pb2, pi1, zin, cb, c2d, idxf, npx, nseg);

        embed_kernel<<<dim3(B * 4), dim3(256), 0, stream>>>(idxf, cb, hu, pn);

        int pn2 = (si < 9) ? PN_[si + 1] : 0;
        conv_tail_kernel<<<dim3(B * 4), dim3(256), 0, stream>>>(
            hu, phiw + PI_[si] * C * C * 9, phib + PI_[si] * C,
            f_hat, f_rest, out, zout, pn, OFF_[si], pn2);
    }
}

// Round 15
// 882.437 us; speedup vs baseline: 1.0842x; 1.0842x over previous
//
#include <hip/hip_runtime.h>

#define B 128
#define C 32
#define HH 16
#define V 4096
#define TB 64
#define CB 256
#define MARGIN 2e-4f

// ---------------- helpers ----------------

__device__ __forceinline__ float cubicw(float t) {
    float at = fabsf(t);
    float at2 = at * at, at3 = at2 * at;
    if (at <= 1.f) return 1.25f * at3 - 2.25f * at2 + 1.f;
    if (at < 2.f)  return -0.75f * at3 + 3.75f * at2 - 6.f * at + 3.f;
    return 0.f;
}

// ---------------- kernels ----------------

// fused setup: f_rest=feat, f_hat=0, c2 (fp64+fp32), stage-0 z (global mean)
__global__ void setup_kernel(const float* __restrict__ feat, float* __restrict__ f_rest,
                             float* __restrict__ f_hat, const float* __restrict__ cb,
                             double* __restrict__ c2d, float* __restrict__ c2f,
                             float* __restrict__ z0) {
    int i = blockIdx.x * 256 + threadIdx.x;
    if (i < B * C * HH * HH) { f_rest[i] = feat[i]; f_hat[i] = 0.f; }
    if (i < V) {
        const float* p = cb + i * C;
        double s = 0.0;
        #pragma unroll
        for (int j = 0; j < C; ++j) { double d = (double)p[j]; s = fma(d, d, s); }
        c2d[i] = s;
        c2f[i] = (float)s;
    }
    if (i < B * C) {
        const float* p = feat + i * (HH * HH);
        float s = 0.f;
        for (int px = 0; px < HH * HH; ++px) s += p[px];
        z0[i] = s * (1.f / 256.f);
    }
}

// ---- GEMM-tiled fp32 top-2 scan (R13 structure: 40 KB LDS, 4 blocks/CU) ----
__global__ __launch_bounds__(256, 4) void scan_gemm_kernel(
    const float* __restrict__ z, const float* __restrict__ cb,
    const float* __restrict__ c2f, float* __restrict__ pb1,
    float* __restrict__ pb2, int* __restrict__ pi1,
    int npx, int nseg, int nblk_tok)
{
    int tid = threadIdx.x;
    int tb  = blockIdx.x % nblk_tok;
    int seg = blockIdx.x / nblk_tok;
    int cps = V / nseg;
    int sb  = seg * cps;
    int t0  = tb * TB;
    int total = B * npx;

    __shared__ float ldsZ[C][TB];
    __shared__ alignas(16) float ldsC[C][CB];
    float* mb1 = &ldsC[0][0];
    float* mb2 = mb1 + 32 * 68;
    int*   mi1 = (int*)(mb2 + 32 * 68);

    #pragma unroll
    for (int i = 0; i < 8; ++i) {
        int e = tid + i * 256;
        int c = e >> 6, t = e & 63;
        int tok = t0 + t;
        int bq = tok / npx, n = tok - bq * npx;
        ldsZ[c][t] = z[(bq * C + c) * npx + n];
    }

    int cg = tid & 31, tg = tid >> 5;

    float b1[8], b2[8]; int i1[8];
    #pragma unroll
    for (int i = 0; i < 8; ++i) { b1[i] = 3e38f; b2[i] = 3e38f; i1[i] = 0; }

    for (int tile = 0; tile < cps / CB; ++tile) {
        int code0 = sb + tile * CB;
        __syncthreads();
        {
            int cc = tid;
            const float4* cp = reinterpret_cast<const float4*>(cb + (size_t)(code0 + cc) * C);
            #pragma unroll
            for (int qq = 0; qq < 8; ++qq) {
                float4 q = cp[qq];
                ldsC[4 * qq + 0][cc] = q.x; ldsC[4 * qq + 1][cc] = q.y;
                ldsC[4 * qq + 2][cc] = q.z; ldsC[4 * qq + 3][cc] = q.w;
            }
        }
        float2 r01 = *reinterpret_cast<const float2*>(&c2f[code0 + 2 * cg]);
        float2 r23 = *reinterpret_cast<const float2*>(&c2f[code0 + 2 * cg + 64]);
        float2 r45 = *reinterpret_cast<const float2*>(&c2f[code0 + 2 * cg + 128]);
        float2 r67 = *reinterpret_cast<const float2*>(&c2f[code0 + 2 * cg + 192]);
        __syncthreads();

        float acc[8][8];
        #pragma unroll
        for (int i = 0; i < 8; ++i)
            #pragma unroll
            for (int j = 0; j < 8; ++j) acc[i][j] = 0.f;

        #pragma unroll 1
        for (int k = 0; k < C; ++k) {
            float4 z0v = *reinterpret_cast<const float4*>(&ldsZ[k][tg * 8]);
            float4 z1v = *reinterpret_cast<const float4*>(&ldsZ[k][tg * 8 + 4]);
            float2 c0 = *reinterpret_cast<const float2*>(&ldsC[k][2 * cg]);
            float2 c1 = *reinterpret_cast<const float2*>(&ldsC[k][2 * cg + 64]);
            float2 c2v = *reinterpret_cast<const float2*>(&ldsC[k][2 * cg + 128]);
            float2 c3 = *reinterpret_cast<const float2*>(&ldsC[k][2 * cg + 192]);
#define FMAROW(ti, zc) \
            acc[ti][0] = fmaf(zc, c0.x, acc[ti][0]); acc[ti][1] = fmaf(zc, c0.y, acc[ti][1]); \
            acc[ti][2] = fmaf(zc, c1.x, acc[ti][2]); acc[ti][3] = fmaf(zc, c1.y, acc[ti][3]); \
            acc[ti][4] = fmaf(zc, c2v.x, acc[ti][4]); acc[ti][5] = fmaf(zc, c2v.y, acc[ti][5]); \
            acc[ti][6] = fmaf(zc, c3.x, acc[ti][6]); acc[ti][7] = fmaf(zc, c3.y, acc[ti][7]);
            FMAROW(0, z0v.x) FMAROW(1, z0v.y) FMAROW(2, z0v.z) FMAROW(3, z0v.w)
            FMAROW(4, z1v.x) FMAROW(5, z1v.y) FMAROW(6, z1v.z) FMAROW(7, z1v.w)
#undef FMAROW
        }

        float rc2[8] = {r01.x, r01.y, r23.x, r23.y, r45.x, r45.y, r67.x, r67.y};
        #pragma unroll
        for (int j = 0; j < 8; ++j) {
            int code = code0 + 2 * cg + (j >> 1) * 64 + (j & 1);
            float cc2 = rc2[j];
            #pragma unroll
            for (int i = 0; i < 8; ++i) {
                float s = fmaf(-2.f, acc[i][j], cc2);
                if (s < b1[i]) { b2[i] = b1[i]; b1[i] = s; i1[i] = code; }
                else if (s < b2[i]) { b2[i] = s; }
            }
        }
    }

    __syncthreads();
    #pragma unroll
    for (int i = 0; i < 8; ++i) {
        mb1[cg * 68 + tg * 8 + i] = b1[i];
        mb2[cg * 68 + tg * 8 + i] = b2[i];
        mi1[cg * 68 + tg * 8 + i] = i1[i];
    }
    __syncthreads();
    if (tid < TB) {
        float gb1 = 3e38f, gb2 = 3e38f; int gi1 = 0;
        #pragma unroll
        for (int g = 0; g < 32; ++g) {
            float v1 = mb1[g * 68 + tid]; int ix = mi1[g * 68 + tid];
            if (v1 < gb1 || (v1 == gb1 && ix < gi1)) { gb2 = gb1; gb1 = v1; gi1 = ix; }
            else if (v1 < gb2) { gb2 = v1; }
            float v2 = mb2[g * 68 + tid];
            if (v2 < gb2) gb2 = v2;
        }
        int tok = t0 + tid;
        pb1[(size_t)seg * total + tok] = gb1;
        pb2[(size_t)seg * total + tok] = gb2;
        pi1[(size_t)seg * total + tok] = gi1;
    }
}

// single fused tail: combine + fp64 recheck + gather + SEPARABLE bicubic + conv
//                    + blend/update + context pool + next-z pool.  B*4 blocks,
//                    8 out-ch each; cheap phases duplicated (launch count wins, R14).
__global__ __launch_bounds__(256) void stage_tail_kernel(
    const float* __restrict__ pb1, const float* __restrict__ pb2,
    const int* __restrict__ pi1, const float* __restrict__ z,
    const float* __restrict__ cb, const double* __restrict__ c2d,
    const float* __restrict__ w, const float* __restrict__ bias,
    float* __restrict__ f_hat, float* __restrict__ f_rest,
    float* __restrict__ out, float* __restrict__ znext,
    int pn, int off, int pn2, int nseg)
{
    int bb = blockIdx.x >> 2;
    int og = (blockIdx.x & 3) * 8;
    int tid = threadIdx.x;
    int npx = pn * pn;
    int total = B * npx;

    __shared__ float A_s[32][260];   // gather -> (dead) -> hu ; rows 16B-aligned
    __shared__ float B_s[32][260];   // v-pass temp -> (dead) -> fh/fr overlay
    __shared__ int idx_s[256];
    __shared__ int flist[256];
    __shared__ int fcnt;
    __shared__ double zsd[C];
    __shared__ double sred[256];
    __shared__ int sidx[256];
    __shared__ float wtab[16][4];
    __shared__ int   itab[16][4];
    float (*fh_s)[260] = &B_s[0];
    float (*fr_s)[260] = &B_s[8];

    // prefetch this block's f_hat/f_rest (latency hides under combine..conv)
    float pf[8], pr[8];
    #pragma unroll
    for (int o = 0; o < 8; ++o) {
        int gi = (bb * 32 + og + o) * 256 + tid;
        pf[o] = f_hat[gi]; pr[o] = f_rest[gi];
    }

    if (tid < 16) {
        float scale = (float)pn * (1.f / 16.f);
        float src = (tid + 0.5f) * scale - 0.5f;
        int fi = (int)floorf(src);
        float t = src - (float)fi;
        #pragma unroll
        for (int k = 0; k < 4; ++k) {
            wtab[tid][k] = cubicw((float)(k - 1) - t);
            itab[tid][k] = min(max(fi + k - 1, 0), pn - 1);
        }
    }
    if (tid == 0) fcnt = 0;
    __syncthreads();

    // 0) combine per-segment top-2 -> idx or ambiguous flag (npx <= 256)
    if (tid < npx) {
        int tok = bb * npx + tid;
        float gb1 = 3e38f, gb2 = 3e38f; int gi1 = 0;
        for (int s = 0; s < nseg; ++s) {
            float v1 = pb1[(size_t)s * total + tok];
            int   ix = pi1[(size_t)s * total + tok];
            if (v1 < gb1 || (v1 == gb1 && ix < gi1)) { gb2 = gb1; gb1 = v1; gi1 = ix; }
            else if (v1 < gb2) { gb2 = v1; }
            float v2 = pb2[(size_t)s * total + tok];
            if (v2 < gb2) gb2 = v2;
        }
        idx_s[tid] = gi1;
        if (gb2 - gb1 < MARGIN) { int slot = atomicAdd(&fcnt, 1); flist[slot] = tid; }
    }
    __syncthreads();

    // 1) exact fp64 rescan for ambiguous tokens (rare at MARGIN 2e-4)
    int nf = fcnt;
    for (int f = 0; f < nf; ++f) {
        int n = flist[f];
        if (tid < C) zsd[tid] = (double)z[(bb * C + tid) * npx + n];
        __syncthreads();
        double best = 1e300; int bi = 0x7fffffff;
        for (int k = 0; k < V / 256; ++k) {
            int v = tid + k * 256;
            const float4* cp = reinterpret_cast<const float4*>(cb + (size_t)v * C);
            double acc = 0.0;
            #pragma unroll
            for (int qq = 0; qq < 8; ++qq) {
                float4 fv = cp[qq];
                acc = fma((double)fv.x, zsd[4 * qq + 0], acc);
                acc = fma((double)fv.y, zsd[4 * qq + 1], acc);
                acc = fma((double)fv.z, zsd[4 * qq + 2], acc);
                acc = fma((double)fv.w, zsd[4 * qq + 3], acc);
            }
            double s = fma(-2.0, acc, c2d[v]);
            if (s < best || (s == best && v < bi)) { best = s; bi = v; }
        }
        sred[tid] = best; sidx[tid] = bi;
        __syncthreads();
        for (int st = 128; st > 0; st >>= 1) {
            if (tid < st) {
                double o = sred[tid + st]; int oi = sidx[tid + st];
                double me = sred[tid];     int mi = sidx[tid];
                if (o < me || (o == me && oi < mi)) { sred[tid] = o; sidx[tid] = oi; }
            }
            __syncthreads();
        }
        if (tid == 0) idx_s[n] = sidx[0];
        __syncthreads();
    }
    __syncthreads();

    // 2) gather all 32 channels: A_s[c][n] = cb[idx[n]][c]
    for (int e = tid; e < 32 * npx; e += 256) {
        int c = e & 31, n = e >> 5;
        A_s[c][n] = cb[idx_s[n] * 32 + c];
    }
    __syncthreads();

    // 3a) separable bicubic v-pass: B_s[c][p*pn+w] = sum_k wtab[p][k]*A_s[c][itab[p][k]*pn+w]
    for (int e = tid; e < 32 * 16 * pn; e += 256) {
        int wx = e % pn; int rest = e / pn;
        int p = rest & 15, c = rest >> 4;
        float s = 0.f;
        #pragma unroll
        for (int k = 0; k < 4; ++k)
            s = fmaf(wtab[p][k], A_s[c][itab[p][k] * pn + wx], s);
        B_s[c][p * pn + wx] = s;
    }
    __syncthreads();

    // 3b) h-pass: A_s[c][p*16+q] = sum_k wtab[q][k]*B_s[c][p*pn+itab[q][k]]  (A_s now = hu)
    #pragma unroll
    for (int it = 0; it < 32; ++it) {
        int e = tid + it * 256;
        int q = e & 15, p = (e >> 4) & 15, c = e >> 8;
        float s = 0.f;
        #pragma unroll
        for (int k = 0; k < 4; ++k)
            s = fmaf(wtab[q][k], B_s[c][p * pn + itab[q][k]], s);
        A_s[c][e & 255] = s;
    }
    __syncthreads();

    // 4) conv 3x3 SAME over 32 in-ch (A_s) for out-ch og..og+7
    int p = tid >> 4, q = tid & 15;
    float acc[8];
    #pragma unroll
    for (int o = 0; o < 8; ++o) acc[o] = bias[og + o];
    for (int i = 0; i < 32; ++i) {
        float v[9];
        #pragma unroll
        for (int dy = 0; dy < 3; ++dy)
            #pragma unroll
            for (int dx = 0; dx < 3; ++dx) {
                int pp = p + dy - 1, qq = q + dx - 1;
                bool in = (pp >= 0) & (pp < 16) & (qq >= 0) & (qq < 16);
                v[dy * 3 + dx] = in ? A_s[i][pp * 16 + qq] : 0.f;
            }
        #pragma unroll
        for (int o = 0; o < 8; ++o) {
            const float* wp_ = w + ((og + o) * 32 + i) * 9;
            #pragma unroll
            for (int k = 0; k < 9; ++k) acc[o] = fmaf(wp_[k], v[k], acc[o]);
        }
    }
    float hv[8];
    #pragma unroll
    for (int o = 0; o < 8; ++o) hv[o] = A_s[og + o][tid];
    __syncthreads();   // all B_s reads (v-pass temp) and A_s reads done

    // 5) blend + update f_hat/f_rest; stage new values into B_s overlay
    #pragma unroll
    for (int o = 0; o < 8; ++o) {
        int gi = (bb * 32 + og + o) * 256 + tid;
        float blend = 0.5f * hv[o] + 0.5f * acc[o];
        float nf = pf[o] + blend;
        float nr = pr[o] - blend;
        f_hat[gi] = nf; f_rest[gi] = nr;
        fh_s[o][tid] = nf; fr_s[o][tid] = nr;
    }
    __syncthreads();

    // 6) context: area-pool new f_hat -> out [B,680,C] transposed slice
    for (int e = tid; e < 8 * npx; e += 256) {
        int o = e & 7, n = e >> 3;
        int y = n / pn, x = n - y * pn;
        int sh = (y * HH) / pn, eh = ((y + 1) * HH + pn - 1) / pn;
        int sw = (x * HH) / pn, ew = ((x + 1) * HH + pn - 1) / pn;
        float s = 0.f;
        for (int yy = sh; yy < eh; ++yy)
            for (int xx = sw; xx < ew; ++xx) s += fh_s[o][yy * 16 + xx];
        out[((bb * 680) + off + n) * 32 + og + o] = s * (1.f / (float)((eh - sh) * (ew - sw)));
    }

    // 7) next-stage z: area-pool new f_rest to pn2 x pn2
    if (pn2 > 0) {
        int npx2 = pn2 * pn2;
        for (int e = tid; e < 8 * npx2; e += 256) {
            int o = e / npx2, n = e - o * npx2;
            int y = n / pn2, x = n - y * pn2;
            int sh = (y * HH) / pn2, eh = ((y + 1) * HH + pn2 - 1) / pn2;
            int sw = (x * HH) / pn2, ew = ((x + 1) * HH + pn2 - 1) / pn2;
            float s = 0.f;
            for (int yy = sh; yy < eh; ++yy)
                for (int xx = sw; xx < ew; ++xx) s += fr_s[o][yy * 16 + xx];
            znext[(bb * 32 + og + o) * npx2 + n] = s * (1.f / (float)((eh - sh) * (ew - sw)));
        }
    }
}

// ---------------- launch ----------------

extern "C" void kernel_launch(void* const* d_in, const int* in_sizes, int n_in,
                              void* d_out, int out_size, void* d_ws, size_t ws_size,
                              hipStream_t stream) {
    const float* feat = (const float*)d_in[0];
    const float* cb   = (const float*)d_in[1];
    const float* phiw = (const float*)d_in[2];
    const float* phib = (const float*)d_in[3];
    float* out = (float*)d_out;
    float* wsf = (float*)d_ws;

    const int NE = B * C * HH * HH; // 1048576
    float* f_rest = wsf;
    float* f_hat  = wsf + NE;
    float* zA     = wsf + 2 * NE;
    float* zB     = wsf + 3 * NE;
    char*  tl     = (char*)(wsf + 4 * NE);
    double* c2d  = (double*)tl;                       // 32 KB
    float*  c2f  = (float*)(tl + (32 << 10));         // 16 KB
    float*  pb1  = (float*)(tl + (48 << 10));                 // 1 MB each (<=346 KB used)
    float*  pb2  = (float*)(tl + (48 << 10) + (1 << 20));
    int*    pi1  = (int*)  (tl + (48 << 10) + (2 << 20));

    static const int PN_[10]   = {1, 2, 3, 4, 5, 6, 8, 10, 13, 16};
    static const int PI_[10]   = {0, 0, 1, 1, 1, 2, 2, 2, 3, 3};
    static const int OFF_[10]  = {0, 1, 5, 14, 30, 55, 91, 155, 255, 424};
    static const int NSEG_[10] = {16, 16, 16, 16, 16, 16, 8, 4, 4, 2};

    setup_kernel<<<dim3((NE + 255) / 256), dim3(256), 0, stream>>>(
        feat, f_rest, f_hat, cb, c2d, c2f, zA);

    for (int si = 0; si < 10; ++si) {
        int pn = PN_[si], npx = pn * pn;
        int tokens = B * npx;
        int nseg = NSEG_[si];
        int nblk_tok = tokens / TB;
        float* zin  = (si & 1) ? zB : zA;
        float* zout = (si & 1) ? zA : zB;

        scan_gemm_kernel<<<dim3(nblk_tok * nseg), dim3(256), 0, stream>>>(
            zin, cb, c2f, pb1, pb2, pi1, npx, nseg, nblk_tok);

        int pn2 = (si < 9) ? PN_[si + 1] : 0;
        stage_tail_kernel<<<dim3(B * 4), dim3(256), 0, stream>>>(
            pb1, pb2, pi1, zin, cb, c2d,
            phiw + PI_[si] * C * C * 9, phib + PI_[si] * C,
            f_hat, f_rest, out, zout, pn, OFF_[si], pn2, nseg);
    }
}